// Round 3
// baseline (539.135 us; speedup 1.0000x reference)
//
#include <hip/hip_runtime.h>
#include <hip/hip_bf16.h>
#include <cstdint>

// ---------- types ----------
typedef __bf16 bf16x8 __attribute__((ext_vector_type(8)));
typedef float  f32x4  __attribute__((ext_vector_type(4)));

typedef __attribute__((address_space(3))) void lds_void;
typedef const __attribute__((address_space(1))) void gbl_cvoid;

#define GLOAD_LDS16(g, l) \
    __builtin_amdgcn_global_load_lds((gbl_cvoid*)(g), (lds_void*)(l), 16, 0, 0)

// Problem constants
static constexpr int IN   = 4096;
static constexpr int OUT  = 4096;
static constexpr int RANK = 256;
static constexpr int M_ROWS = 4 * 2048;  // B*S = 8192

// ---------- device helpers ----------
__device__ __forceinline__ void cast8(const float* __restrict__ in,
                                      __bf16* __restrict__ out, int t) {
    const float4* p = (const float4*)in + (size_t)t * 2;
    float4 v0 = p[0], v1 = p[1];
    bf16x8 o;
    o[0] = (__bf16)v0.x; o[1] = (__bf16)v0.y; o[2] = (__bf16)v0.z; o[3] = (__bf16)v0.w;
    o[4] = (__bf16)v1.x; o[5] = (__bf16)v1.y; o[6] = (__bf16)v1.z; o[7] = (__bf16)v1.w;
    ((bf16x8*)out)[t] = o;
}

// ---------- kernel 1: prep = cast B (blocks 0..511) + make AdT (blocks 512..767) ----
__global__ __launch_bounds__(256) void prep(
    const float* __restrict__ Bm, __bf16* __restrict__ Bbf,
    const float* __restrict__ A,  const float* __restrict__ d,
    __bf16* __restrict__ AdT)
{
    __shared__ float tile[64][65];
    const int blk = blockIdx.x;
    const int t   = threadIdx.x;

    if (blk < 512) {                     // cast B: 1,048,576 elems / 8
        cast8(Bm, Bbf, blk * 256 + t);
        return;
    }
    const int ab = blk - 512;            // 0..255
    const int i0 = (ab & 63) * 64;
    const int r0 = (ab >> 6) * 64;
    const int cl = t & 63;
    const int rw = t >> 6;

#pragma unroll
    for (int it = 0; it < 16; ++it) {
        int rl = it * 4 + rw;
        tile[rl][cl] = A[(size_t)(r0 + rl) * IN + i0 + cl];
    }
    __syncthreads();
    float dv = d[r0 + cl];
#pragma unroll
    for (int it = 0; it < 16; ++it) {
        int il = it * 4 + rw;
        AdT[(size_t)(i0 + il) * RANK + r0 + cl] = (__bf16)(tile[cl][il] * dv);
    }
}

// ---------- kernel 2: fused Weff-GEMM (blocks 0..1023) + cast x (rest) ----------
// Weff[o][i] = bf16( W[o][i] + sum_r Bw[o][r]*AdT[i][r] )  (128x128 tile, verified)
__global__ __launch_bounds__(256) void weff_cast(
    const __bf16* __restrict__ Bw,   // [OUT, RANK] bf16
    const __bf16* __restrict__ AdT,  // [IN,  RANK] bf16
    const float*  __restrict__ W,    // [OUT, IN] fp32
    __bf16* __restrict__ Weff,       // [OUT, IN] bf16
    const float*  __restrict__ x,    // [8192, 4096] fp32
    __bf16* __restrict__ x_bf)       // [8192, 4096] bf16
{
    __shared__ __bf16 sA[128 * 64];
    __shared__ __bf16 sB[128 * 64];

    const int blk = blockIdx.x;
    const int t   = threadIdx.x;

    if (blk >= 1024) {                   // cast x: 33,554,432 elems / 8
        cast8(x, x_bf, (blk - 1024) * 256 + t);
        return;
    }

    constexpr int K = RANK;   // 256
    const int wave = t >> 6;
    const int lane = t & 63;
    const int quad = lane >> 4;
    const int l16  = lane & 15;
    const int m0 = (blk >> 5) * 128;   // o
    const int n0 = (blk & 31) * 128;   // i
    const int wm = (wave >> 1) * 64;
    const int wn = (wave & 1) * 64;
    const int xr = l16 & 7;

    f32x4 acc[4][4] = {};

    for (int kt = 0; kt < K; kt += 64) {
#pragma unroll
        for (int j = 0; j < 4; ++j) {
            int ci  = j * 256 + t;
            int row = ci >> 3;
            int kc  = (ci & 7) ^ (row & 7);
            GLOAD_LDS16(Bw  + (size_t)(m0 + row) * K + kt + kc * 8, sA + ci * 8);
        }
#pragma unroll
        for (int j = 0; j < 4; ++j) {
            int ci  = j * 256 + t;
            int row = ci >> 3;
            int kc  = (ci & 7) ^ (row & 7);
            GLOAD_LDS16(AdT + (size_t)(n0 + row) * K + kt + kc * 8, sB + ci * 8);
        }
        __syncthreads();

#pragma unroll
        for (int kk = 0; kk < 64; kk += 32) {
            const int kb = kk >> 3;
            bf16x8 a[4], b[4];
#pragma unroll
            for (int mi = 0; mi < 4; ++mi)
                a[mi] = *(const bf16x8*)(sA + (wm + mi * 16 + l16) * 64 + (((kb + quad) ^ xr) << 3));
#pragma unroll
            for (int ni = 0; ni < 4; ++ni)
                b[ni] = *(const bf16x8*)(sB + (wn + ni * 16 + l16) * 64 + (((kb + quad) ^ xr) << 3));
#pragma unroll
            for (int mi = 0; mi < 4; ++mi)
#pragma unroll
                for (int ni = 0; ni < 4; ++ni)
                    acc[mi][ni] = __builtin_amdgcn_mfma_f32_16x16x32_bf16(a[mi], b[ni], acc[mi][ni], 0, 0, 0);
        }
        __syncthreads();
    }

#pragma unroll
    for (int mi = 0; mi < 4; ++mi) {
#pragma unroll
        for (int r = 0; r < 4; ++r) {
            int row = m0 + wm + mi * 16 + quad * 4 + r;
#pragma unroll
            for (int ni = 0; ni < 4; ++ni) {
                int col = n0 + wn + ni * 16 + l16;
                size_t idx = (size_t)row * IN + col;
                Weff[idx] = (__bf16)(acc[mi][ni][r] + W[idx]);
            }
        }
    }
}

// ---------- kernel 3: out[m][n] = sum_k X[m][k]*Weff[n][k] + bias[n] ----------
// 256x256 tile, BK=32, 8 waves (2Mx4N), 512 threads, 4-deep LDS ring (128 KiB).
// R3 restructure: DECOUPLED READ/MFMA PIPELINE (1 barrier per K-tile).
//   R1/R2 diagnosis: 2475 cyc/tile = LDS-read time (768-1152) + MFMA time (1242)
//   SERIALIZED by the 4-barrier lockstep (all waves read, then all waves MFMA).
//   New per-tile schedule (reads always issued one MFMA-phase before use;
//   compiler's counted lgkmcnt does the waits):
//     VM(4); barrier;                   // stage(t+1) landed globally
//     read aH (p2 frags, buf t); stage(t+3);
//     MFMA p1 (aL, b_cur);              // aH reads drain underneath
//     read aL'+b_nxt (tile t+1 p1 frags, buf t+1);
//     MFMA p2 (aH, b_cur);              // t+1 reads drain underneath
//   B-frags ping-pong (bx/by, +16 VGPR); aL/aH reuse in place (WAR = program order).
//   Ledger (4 gload_lds/thread/tile): at tile top in-flight = stage(t+1)+stage(t+2)
//   = 8 -> VM(4) retires stage(t+1). Stage into buf(t+3) safe: all reads of its old
//   tile (t-1) drained before the PREVIOUS tile's top barrier. Epilogue VM(4),VM(4),
//   VM(0),none. Prologue VM(8) also drains prior tp's C-stores (in-order vmcnt).
//   Addressing/swizzle identical to verified R1/R2 (0 bank conflicts).

#define LD_A(BUF, mi) (*(const bf16x8*)&sX[BUF][abase + (mi) * 512])
#define LD_B(BUF, ni) (*(const bf16x8*)&sW[BUF][bbase + (ni) * 512])
#define BARR() __builtin_amdgcn_s_barrier()
#define VM(N)  asm volatile("s_waitcnt vmcnt(" #N ")")

#define STG_X(BUF, P) do { \
    GLOAD_LDS16((P),          &sX[BUF][tid * 8]); \
    GLOAD_LDS16((P) + 524288, &sX[BUF][4096 + tid * 8]); \
} while (0)
#define STG_W(BUF, P) do { \
    GLOAD_LDS16((P),          &sW[BUF][tid * 8]); \
    GLOAD_LDS16((P) + 524288, &sW[BUF][4096 + tid * 8]); \
} while (0)

#define MROW(mi, A, c0, c1, c2, c3) \
    acc[mi][0] = __builtin_amdgcn_mfma_f32_16x16x32_bf16(A, c0, acc[mi][0], 0, 0, 0); \
    acc[mi][1] = __builtin_amdgcn_mfma_f32_16x16x32_bf16(A, c1, acc[mi][1], 0, 0, 0); \
    acc[mi][2] = __builtin_amdgcn_mfma_f32_16x16x32_bf16(A, c2, acc[mi][2], 0, 0, 0); \
    acc[mi][3] = __builtin_amdgcn_mfma_f32_16x16x32_bf16(A, c3, acc[mi][3], 0, 0, 0);

// One K-tile: uses buf BUF with b-set (c0..c3); prefetches tile t+1 p1 frags
// from NBUF into aL and the OTHER b-set (n0_..n3_).
#define TILE_P(BUF, NBUF, c0, c1, c2, c3, n0_, n1_, n2_, n3_, STG, VMS) \
    { \
        VMS; \
        BARR(); \
        aH0 = LD_A(BUF, 4); aH1 = LD_A(BUF, 5); aH2 = LD_A(BUF, 6); aH3 = LD_A(BUF, 7); \
        STG; \
        __builtin_amdgcn_s_setprio(1); \
        MROW(0, aL0, c0, c1, c2, c3) MROW(1, aL1, c0, c1, c2, c3) \
        MROW(2, aL2, c0, c1, c2, c3) MROW(3, aL3, c0, c1, c2, c3) \
        __builtin_amdgcn_s_setprio(0); \
        aL0 = LD_A(NBUF, 0); aL1 = LD_A(NBUF, 1); aL2 = LD_A(NBUF, 2); aL3 = LD_A(NBUF, 3); \
        n0_ = LD_B(NBUF, 0); n1_ = LD_B(NBUF, 1); n2_ = LD_B(NBUF, 2); n3_ = LD_B(NBUF, 3); \
        __builtin_amdgcn_s_setprio(1); \
        MROW(4, aH0, c0, c1, c2, c3) MROW(5, aH1, c0, c1, c2, c3) \
        MROW(6, aH2, c0, c1, c2, c3) MROW(7, aH3, c0, c1, c2, c3) \
        __builtin_amdgcn_s_setprio(0); \
        __builtin_amdgcn_sched_barrier(0); \
    }

__global__ __launch_bounds__(512, 2) void main_gemm(
    const __bf16* __restrict__ X,     // [8192, 4096] bf16
    const __bf16* __restrict__ Wf,    // [4096, 4096] bf16
    const float*  __restrict__ bias,  // [4096]
    float* __restrict__ out)          // [8192, 4096] fp32
{
    constexpr int K = IN;     // 4096
    constexpr int N = OUT;    // 4096
    __shared__ __bf16 sX[4][8192];    // 4 bufs x 256 rows x 32 k  (64 KiB)
    __shared__ __bf16 sW[4][8192];    // 4 bufs x 256 rows x 32 k  (64 KiB)

    const int tid  = threadIdx.x;
    const int lane = tid & 63;
    const int quad = lane >> 4;
    const int l16  = lane & 15;
    const int wave = tid >> 6;
    const int wmb  = (wave >> 2) * 128;   // wave's M offset within tile
    const int wnb  = (wave & 3) * 64;     // wave's N offset within tile

    // XCD-aware persistent-block decode (bijective: blk = c | (i<<3))
    const int blk    = blockIdx.x;        // 0..255, HW: XCD = blk & 7
    const int c      = blk & 7;
    const int i      = blk >> 3;          // 0..31
    const int n0     = (c * 2 + (i & 1)) * 256;
    const int m_base = (i >> 1) * 256;

    // fragment read addressing (slot is thread-constant: single K-step per tile)
    const int slot  = quad ^ ((l16 >> 1) & 3);
    const int abase = (wmb + l16) * 32 + slot * 8;
    const int bbase = (wnb + l16) * 32 + slot * 8;

    // stage addressing: linear LDS dst, pre-swizzled global source chunk
    const int row0 = tid >> 2;                          // 0..127 (j=1 adds 128)
    const int ch0  = (tid & 3) ^ ((row0 >> 1) & 3);     // same for both j halves
    const __bf16* wsrc = Wf + (size_t)(n0 + row0) * K + ch0 * 8;

    float bv[4];
#pragma unroll
    for (int ni = 0; ni < 4; ++ni)
        bv[ni] = bias[n0 + wnb + ni * 16 + l16];

#pragma unroll 1
    for (int tp = 0; tp < 2; ++tp) {
        const int m0 = m_base + tp * 4096;
        const __bf16* xsrc = X + (size_t)(m0 + row0) * K + ch0 * 8;

        f32x4 acc[8][4] = {};
        bf16x8 aL0, aL1, aL2, aL3, aH0, aH1, aH2, aH3;
        bf16x8 bx0, bx1, bx2, bx3, by0, by1, by2, by3;

        // prologue: stage tiles 0,1,2; VM(8) = stage(0) landed (also drains prior
        // tp's C-stores, in-order); barrier; then issue tile-0 p1 frag reads.
        STG_X(0, xsrc);      STG_W(0, wsrc);
        STG_X(1, xsrc + 32); STG_W(1, wsrc + 32);
        STG_X(2, xsrc + 64); STG_W(2, wsrc + 64);
        VM(8);
        BARR();
        aL0 = LD_A(0, 0); aL1 = LD_A(0, 1); aL2 = LD_A(0, 2); aL3 = LD_A(0, 3);
        bx0 = LD_B(0, 0); bx1 = LD_B(0, 1); bx2 = LD_B(0, 2); bx3 = LD_B(0, 3);

        const __bf16* xs = xsrc + 96;   // next stage = tile 3
        const __bf16* ws = wsrc + 96;

        // main loop: tiles 0..123 (31 iters x 4), stage lookahead = 3 tiles
#pragma unroll 1
        for (int it = 0; it < 31; ++it) {
            TILE_P(0, 1, bx0, bx1, bx2, bx3, by0, by1, by2, by3,
                   STG_X(3, xs); STG_W(3, ws), VM(4))
            TILE_P(1, 2, by0, by1, by2, by3, bx0, bx1, bx2, bx3,
                   STG_X(0, xs + 32); STG_W(0, ws + 32), VM(4))
            TILE_P(2, 3, bx0, bx1, bx2, bx3, by0, by1, by2, by3,
                   STG_X(1, xs + 64); STG_W(1, ws + 64), VM(4))
            TILE_P(3, 0, by0, by1, by2, by3, bx0, bx1, bx2, bx3,
                   STG_X(2, xs + 96); STG_W(2, ws + 96), VM(4))
            xs += 128; ws += 128;
        }

        // epilogue: tiles 124..127; tile 124 stages 127; drain VM(4),VM(4),VM(0)
        TILE_P(0, 1, bx0, bx1, bx2, bx3, by0, by1, by2, by3,
               STG_X(3, xs); STG_W(3, ws), VM(4))
        TILE_P(1, 2, by0, by1, by2, by3, bx0, bx1, bx2, bx3, (void)0, VM(4))
        TILE_P(2, 3, bx0, bx1, bx2, bx3, by0, by1, by2, by3, (void)0, VM(0))
        // tile 127 (uses by, no prefetch)
        {
            BARR();
            aH0 = LD_A(3, 4); aH1 = LD_A(3, 5); aH2 = LD_A(3, 6); aH3 = LD_A(3, 7);
            __builtin_amdgcn_s_setprio(1);
            MROW(0, aL0, by0, by1, by2, by3) MROW(1, aL1, by0, by1, by2, by3)
            MROW(2, aL2, by0, by1, by2, by3) MROW(3, aL3, by0, by1, by2, by3)
            MROW(4, aH0, by0, by1, by2, by3) MROW(5, aH1, by0, by1, by2, by3)
            MROW(6, aH2, by0, by1, by2, by3) MROW(7, aH3, by0, by1, by2, by3)
            __builtin_amdgcn_s_setprio(0);
        }

        // C-write (stores left in flight; next tp's prologue VM(8) drains them)
#pragma unroll
        for (int mi = 0; mi < 8; ++mi) {
#pragma unroll
            for (int r = 0; r < 4; ++r) {
                int row = m0 + wmb + mi * 16 + quad * 4 + r;
#pragma unroll
                for (int ni = 0; ni < 4; ++ni) {
                    int col = n0 + wnb + ni * 16 + l16;
                    out[(size_t)row * N + col] = acc[mi][ni][r] + bv[ni];
                }
            }
        }
    }
}

#undef TILE_P
#undef MROW
#undef STG_X
#undef STG_W
#undef LD_A
#undef LD_B
#undef BARR
#undef VM

// ---------- launch ----------
extern "C" void kernel_launch(void* const* d_in, const int* in_sizes, int n_in,
                              void* d_out, int out_size, void* d_ws, size_t ws_size,
                              hipStream_t stream) {
    const float* x  = (const float*)d_in[0];   // [8192, 4096]
    const float* W  = (const float*)d_in[1];   // [4096, 4096]
    const float* A  = (const float*)d_in[2];   // [256, 4096]
    const float* Bm = (const float*)d_in[3];   // [4096, 256]
    const float* d  = (const float*)d_in[4];   // [256]
    const float* b  = (const float*)d_in[5];   // [4096]
    float* out = (float*)d_out;

    // workspace layout
    char* ws = (char*)d_ws;
    __bf16* x_bf   = (__bf16*)(ws);                                  // 67,108,864 B
    __bf16* weff   = (__bf16*)(ws + (size_t)67108864);               // 33,554,432 B
    __bf16* b_bf   = (__bf16*)(ws + (size_t)67108864 + 33554432);    //  2,097,152 B
    __bf16* adt_bf = (__bf16*)(ws + (size_t)67108864 + 33554432 + 2097152); // 2,097,152 B

    // 1) prep: cast B (512 blocks) + AdT transpose (256 blocks)
    prep<<<768, 256, 0, stream>>>(Bm, b_bf, A, d, adt_bf);
    // 2) fused: Weff GEMM (1024 blocks) + cast x (16384 blocks)
    weff_cast<<<1024 + 16384, 256, 0, stream>>>(b_bf, adt_bf, W, weff, x, x_bf);
    // 3) out = x_bf @ Weff^T + b   (256^2 tile, decoupled read/MFMA pipeline)
    main_gemm<<<256, 512, 0, stream>>>(x_bf, weff, b, out);
}